// Round 1
// baseline (501.046 us; speedup 1.0000x reference)
//
#include <hip/hip_runtime.h>

#define D 128
#define KNBR 32
#define BATCH 8192
#define NCLASS 60
#define NB 16      // b rows per block (k_gemm)
#define NP 32      // (b, side) pairs per block (k_gemm)

// ---------------------------------------------------------------------------
// K0: prep. blk0: wqa = Wq@a[:D], wka = Wk@a[D:]
//          blk1: be = We_b @ Wuc[384:512]
//          blks 2..49: Wcomb2 = [Wk@Wuc[128:256]; Wk@Wuc[256:384]; We_w@Wuc[384:512]]
__global__ __launch_bounds__(256) void k_prep(
    const float* __restrict__ Wq, const float* __restrict__ Wk,
    const float* __restrict__ a, const float* __restrict__ Wew,
    const float* __restrict__ Web, const float* __restrict__ Wuc,
    float* __restrict__ wqa, float* __restrict__ wka,
    float* __restrict__ be, float* __restrict__ Wcomb2)
{
    __shared__ float sB[128][129];
    int blk = blockIdx.x, tid = threadIdx.x;
    if (blk == 0) {
        for (int t = tid; t < 128 * 128; t += 256) sB[t >> 7][t & 127] = Wq[t];
        __syncthreads();
        if (tid < 128) {
            float s = 0.f;
            for (int j = 0; j < D; ++j) s += sB[tid][j] * a[j];
            wqa[tid] = s;
        }
        __syncthreads();
        for (int t = tid; t < 128 * 128; t += 256) sB[t >> 7][t & 127] = Wk[t];
        __syncthreads();
        if (tid < 128) {
            float s = 0.f;
            for (int j = 0; j < D; ++j) s += sB[tid][j] * a[D + j];
            wka[tid] = s;
        }
    } else if (blk == 1) {
        if (tid < 128) {
            float acc = 0.f;
            for (int j = 0; j < D; ++j) acc += Web[j] * Wuc[(size_t)(384 + j) * D + tid];
            be[tid] = acc;
        }
    } else {
        int g  = (blk - 2) >> 4;
        int rb = ((blk - 2) & 15) * 8;
        const float* A = (g == 2) ? Wew : Wk;
        const float* B = Wuc + (size_t)(128 + g * 128) * D;
        for (int t = tid; t < 128 * 128; t += 256) sB[t >> 7][t & 127] = B[t];
        __syncthreads();
        int j = tid & 127, half = tid >> 7;
        float acc[4] = {0.f, 0.f, 0.f, 0.f};
        int r0 = rb + half * 4;
        for (int t = 0; t < 128; ++t) {
            float bv = sB[t][j];
            #pragma unroll
            for (int m = 0; m < 4; ++m)
                acc[m] = fmaf(A[(size_t)(r0 + m) * D + t], bv, acc[m]);
        }
        #pragma unroll
        for (int m = 0; m < 4; ++m)
            Wcomb2[(size_t)(g * 128 + r0 + m) * D + j] = acc[m];
    }
}

// ---------------------------------------------------------------------------
// K1: per-node scores: sq[n] = mem[n].wqa, sk[n] = mem[n].wka.
// Streams the full node table once, coalesced. 3125 blocks x 64 nodes.
__global__ __launch_bounds__(256) void k_scores(
    const float* __restrict__ mem,
    const float* __restrict__ wqa, const float* __restrict__ wka,
    float* __restrict__ nsq, float* __restrict__ nsk)
{
    int tid = threadIdx.x, lane = tid & 31, grp = tid >> 5;
    int n0 = blockIdx.x * 64 + grp * 8;
    float4 wq4 = ((const float4*)wqa)[lane];
    float4 wk4 = ((const float4*)wka)[lane];
    #pragma unroll
    for (int i = 0; i < 8; ++i) {
        int n = n0 + i;
        float4 v = ((const float4*)(mem + (size_t)n * D))[lane];
        float pq = v.x * wq4.x + v.y * wq4.y + v.z * wq4.z + v.w * wq4.w;
        float pk = v.x * wk4.x + v.y * wk4.y + v.z * wk4.z + v.w * wk4.w;
        #pragma unroll
        for (int m = 1; m <= 16; m <<= 1) {
            pq += __shfl_xor(pq, m, 32);
            pk += __shfl_xor(pk, m, 32);
        }
        if (lane == 0) nsq[n] = pq;
        if (lane == 1) nsk[n] = pk;
    }
}

// ---------------------------------------------------------------------------
// K2a: attention + weighted neighbor gather, one 32-lane group per (b,side)
// pair. No LDS, no barriers — pure latency machine. 2048 blocks (8 blocks/CU
// worth of grid), 8-deep unrolled row gathers keep O(100 KB)/CU in flight.
// Writes agg[side*B + b][128] row-major (coalesced float4 stores).
__global__ __launch_bounds__(256) void k_attn(
    const float* __restrict__ mem,
    const float* __restrict__ nsq, const float* __restrict__ nsk,
    const int* __restrict__ src_idxs, const int* __restrict__ dst_idxs,
    const int* __restrict__ src_nb, const int* __restrict__ dst_nb,
    float* __restrict__ agg)
{
    int lane = threadIdx.x & 31;
    int grp  = threadIdx.x >> 5;
    int p    = blockIdx.x * 8 + grp;          // 0 .. 2*BATCH-1
    int side = p >> 13;                        // BATCH = 8192
    int b    = p & (BATCH - 1);

    int self_idx = (side ? dst_idxs : src_idxs)[b];
    int ik = (side ? dst_nb : src_nb)[(size_t)b * KNBR + lane];

    float x = nsq[self_idx] + nsk[ik];
    x = (x >= 0.f) ? x : 0.2f * x;             // leaky_relu(0.2)
    float mx = x;
    #pragma unroll
    for (int m = 1; m <= 16; m <<= 1) mx = fmaxf(mx, __shfl_xor(mx, m, 32));
    float e = __expf(x - mx);
    float s = e;
    #pragma unroll
    for (int m = 1; m <= 16; m <<= 1) s += __shfl_xor(s, m, 32);
    float attn = e / s;

    float4 acc = make_float4(0.f, 0.f, 0.f, 0.f);
    #pragma unroll 8
    for (int k = 0; k < KNBR; ++k) {
        int   ikk = __shfl(ik, k, 32);
        float ak  = __shfl(attn, k, 32);
        float4 v = ((const float4*)(mem + (size_t)ikk * D))[lane];
        acc.x = fmaf(ak, v.x, acc.x);
        acc.y = fmaf(ak, v.y, acc.y);
        acc.z = fmaf(ak, v.z, acc.z);
        acc.w = fmaf(ak, v.w, acc.w);
    }
    ((float4*)(agg + (size_t)p * D))[lane] = acc;
}

// ---------------------------------------------------------------------------
// K2b: msg + cls GEMMs. 16 b's x 2 sides per block. agg staged coalesced from
// workspace into the transposed LDS layout the GEMM consumes.
__global__ __launch_bounds__(256, 3) void k_gemm(
    const float* __restrict__ mem, const float* __restrict__ edge_feat,
    const float* __restrict__ Wuc, const float* __restrict__ Wcomb2,
    const float* __restrict__ be, const float* __restrict__ agg,
    const float* __restrict__ Wc1, const float* __restrict__ Wc2,
    const int* __restrict__ src_idxs, const int* __restrict__ dst_idxs,
    const int* __restrict__ edge_idxs,
    float* __restrict__ out)
{
    __shared__ __align__(16) float Ws[32 * 128];     // 16384 B
    __shared__ __align__(16) float nbT[128 * 33];    // 16896 B  [col][pair]
    __shared__ __align__(16) float uni[128 * 33];    // 16896 B  Ast (32x33) / msgT (128x33)
    __shared__ int s_sidx[NP];
    __shared__ int s_eidx[NB];

    int tid = threadIdx.x;
    int b0 = blockIdx.x * NB;
    int lane = tid & 31;
    int grp  = tid >> 5;

    if (tid < NP) s_sidx[tid] = ((tid >> 4) ? dst_idxs : src_idxs)[b0 + (tid & 15)];
    if (tid < NB) s_eidx[tid] = edge_idxs[b0 + tid];

    // ---------------- stage aggT from workspace (coalesced), transposed
    #pragma unroll
    for (int q = 0; q < 4; ++q) {
        int pp = grp + 8 * q;                              // 0..31
        int gp = ((pp >> 4) ? BATCH : 0) + b0 + (pp & 15); // global pair id
        float4 v = ((const float4*)(agg + (size_t)gp * D))[lane];
        nbT[(lane * 4 + 0) * 33 + pp] = v.x;
        nbT[(lane * 4 + 1) * 33 + pp] = v.y;
        nbT[(lane * 4 + 2) * 33 + pp] = v.z;
        nbT[(lane * 4 + 3) * 33 + pp] = v.w;
    }
    __syncthreads();

    // ---------------- Phase B: msg = relu(A @ [Wuc; Wcomb2] + be), A = [32 x 512]
    int tr = tid >> 4, tc = tid & 15;          // 16x16 micro grid, 2 rows x 8 cols
    int lc = tid & 31, lr = tid >> 5;          // A staging lanes
    int wc = tid & 127, wk2 = tid >> 7;        // W staging lanes
    float accB[2][8];
    #pragma unroll
    for (int i = 0; i < 2; ++i)
        #pragma unroll
        for (int j = 0; j < 8; ++j) accB[i][j] = 0.f;

    float* Ast = uni;

    // seg 0 (kt 0..3): A = self rows, staged from mem
    for (int kt = 0; kt < 4; ++kt) {
        int off = kt * 32;
        #pragma unroll
        for (int q = 0; q < 4; ++q) {
            int r = lr + 8 * q;
            Ast[lc * 33 + r] = mem[(size_t)s_sidx[r] * D + off + lc];
        }
        #pragma unroll
        for (int pp = 0; pp < 16; ++pp) {
            int kk = wk2 + 2 * pp;
            Ws[kk * 128 + wc] = Wuc[(size_t)(off + kk) * D + wc];
        }
        __syncthreads();
        #pragma unroll 8
        for (int kk = 0; kk < 32; ++kk) {
            float a0 = Ast[kk * 33 + tr * 2];
            float a1 = Ast[kk * 33 + tr * 2 + 1];
            float4 w0 = *(const float4*)&Ws[kk * 128 + tc * 4];
            float4 w1 = *(const float4*)&Ws[kk * 128 + 64 + tc * 4];
            float wr[8] = {w0.x, w0.y, w0.z, w0.w, w1.x, w1.y, w1.z, w1.w};
            #pragma unroll
            for (int j = 0; j < 8; ++j) {
                accB[0][j] = fmaf(a0, wr[j], accB[0][j]);
                accB[1][j] = fmaf(a1, wr[j], accB[1][j]);
            }
        }
        __syncthreads();
    }
    // segs 1-2 (kt 4..11): A read directly from nbT (no staging)
    for (int kt = 4; kt < 12; ++kt) {
        int off = (kt & 3) * 32;
        int gr0 = kt * 32 - 128;
        #pragma unroll
        for (int pp = 0; pp < 16; ++pp) {
            int kk = wk2 + 2 * pp;
            Ws[kk * 128 + wc] = Wcomb2[(size_t)(gr0 + kk) * D + wc];
        }
        __syncthreads();
        int r0 = (kt < 8) ? (tr * 2) : ((tr * 2) ^ 16);
        #pragma unroll 8
        for (int kk = 0; kk < 32; ++kk) {
            float a0 = nbT[(off + kk) * 33 + r0];
            float a1 = nbT[(off + kk) * 33 + r0 + 1];
            float4 w0 = *(const float4*)&Ws[kk * 128 + tc * 4];
            float4 w1 = *(const float4*)&Ws[kk * 128 + 64 + tc * 4];
            float wr[8] = {w0.x, w0.y, w0.z, w0.w, w1.x, w1.y, w1.z, w1.w};
            #pragma unroll
            for (int j = 0; j < 8; ++j) {
                accB[0][j] = fmaf(a0, wr[j], accB[0][j]);
                accB[1][j] = fmaf(a1, wr[j], accB[1][j]);
            }
        }
        __syncthreads();
    }
    // seg 3 (kt 12..15): A = edge rows, staged from edge_feat
    for (int kt = 12; kt < 16; ++kt) {
        int off = (kt & 3) * 32;
        int gr0 = kt * 32 - 128;
        #pragma unroll
        for (int q = 0; q < 4; ++q) {
            int r = lr + 8 * q;
            Ast[lc * 33 + r] = edge_feat[(size_t)s_eidx[r & 15] * D + off + lc];
        }
        #pragma unroll
        for (int pp = 0; pp < 16; ++pp) {
            int kk = wk2 + 2 * pp;
            Ws[kk * 128 + wc] = Wcomb2[(size_t)(gr0 + kk) * D + wc];
        }
        __syncthreads();
        #pragma unroll 8
        for (int kk = 0; kk < 32; ++kk) {
            float a0 = Ast[kk * 33 + tr * 2];
            float a1 = Ast[kk * 33 + tr * 2 + 1];
            float4 w0 = *(const float4*)&Ws[kk * 128 + tc * 4];
            float4 w1 = *(const float4*)&Ws[kk * 128 + 64 + tc * 4];
            float wr[8] = {w0.x, w0.y, w0.z, w0.w, w1.x, w1.y, w1.z, w1.w};
            #pragma unroll
            for (int j = 0; j < 8; ++j) {
                accB[0][j] = fmaf(a0, wr[j], accB[0][j]);
                accB[1][j] = fmaf(a1, wr[j], accB[1][j]);
            }
        }
        __syncthreads();
    }

    // bias + relu -> msgT[col][row]  (uni: Ast is dead, last read was pre-sync)
    float* msgT = uni;
    {
        float4 bv0 = *(const float4*)&be[tc * 4];
        float4 bv1 = *(const float4*)&be[64 + tc * 4];
        float b8[8] = {bv0.x, bv0.y, bv0.z, bv0.w, bv1.x, bv1.y, bv1.z, bv1.w};
        #pragma unroll
        for (int i = 0; i < 2; ++i) {
            int r = tr * 2 + i;
            #pragma unroll
            for (int j = 0; j < 4; ++j) {
                msgT[(tc * 4 + j) * 33 + r]      = fmaxf(accB[i][j] + b8[j], 0.f);
                msgT[(64 + tc * 4 + j) * 33 + r] = fmaxf(accB[i][j + 4] + b8[j + 4], 0.f);
            }
        }
    }
    __syncthreads();

    // ---------------- Phase C: GEMM1 h1 = relu(msg @ Wc1)
    float accC[2][8];
    #pragma unroll
    for (int i = 0; i < 2; ++i)
        #pragma unroll
        for (int j = 0; j < 8; ++j) accC[i][j] = 0.f;

    for (int kt = 0; kt < 4; ++kt) {
        int off = kt * 32;
        #pragma unroll
        for (int pp = 0; pp < 16; ++pp) {
            int kk = wk2 + 2 * pp;
            Ws[kk * 128 + wc] = Wc1[(size_t)(off + kk) * D + wc];
        }
        __syncthreads();
        #pragma unroll 8
        for (int kk = 0; kk < 32; ++kk) {
            float a0 = msgT[(off + kk) * 33 + tr * 2];
            float a1 = msgT[(off + kk) * 33 + tr * 2 + 1];
            float4 w0 = *(const float4*)&Ws[kk * 128 + tc * 4];
            float4 w1 = *(const float4*)&Ws[kk * 128 + 64 + tc * 4];
            float wr[8] = {w0.x, w0.y, w0.z, w0.w, w1.x, w1.y, w1.z, w1.w};
            #pragma unroll
            for (int j = 0; j < 8; ++j) {
                accC[0][j] = fmaf(a0, wr[j], accC[0][j]);
                accC[1][j] = fmaf(a1, wr[j], accC[1][j]);
            }
        }
        __syncthreads();
    }
    // relu -> h1T overwrites msgT
    #pragma unroll
    for (int i = 0; i < 2; ++i) {
        int r = tr * 2 + i;
        #pragma unroll
        for (int j = 0; j < 4; ++j) {
            msgT[(tc * 4 + j) * 33 + r]      = fmaxf(accC[i][j], 0.f);
            msgT[(64 + tc * 4 + j) * 33 + r] = fmaxf(accC[i][j + 4], 0.f);
        }
    }
    __syncthreads();

    // ---------------- Phase C: GEMM2 logits = h1 @ Wc2  [32x128]@[128x60]
    int r2 = tid & 31;
    int cs = tid >> 5;
    float acc2[8];
    #pragma unroll
    for (int j = 0; j < 8; ++j) acc2[j] = 0.f;

    for (int kt = 0; kt < 4; ++kt) {
        int off = kt * 32;
        for (int t = tid; t < 32 * 64; t += 256) {
            int kk = t >> 6, c = t & 63;
            Ws[t] = (c < NCLASS) ? Wc2[(size_t)(off + kk) * NCLASS + c] : 0.f;
        }
        __syncthreads();
        #pragma unroll 4
        for (int kk = 0; kk < 32; ++kk) {
            float h = msgT[(off + kk) * 33 + r2];
            float4 w0 = *(const float4*)&Ws[kk * 64 + cs * 8];
            float4 w1 = *(const float4*)&Ws[kk * 64 + cs * 8 + 4];
            acc2[0] = fmaf(h, w0.x, acc2[0]);
            acc2[1] = fmaf(h, w0.y, acc2[1]);
            acc2[2] = fmaf(h, w0.z, acc2[2]);
            acc2[3] = fmaf(h, w0.w, acc2[3]);
            acc2[4] = fmaf(h, w1.x, acc2[4]);
            acc2[5] = fmaf(h, w1.y, acc2[5]);
            acc2[6] = fmaf(h, w1.z, acc2[6]);
            acc2[7] = fmaf(h, w1.w, acc2[7]);
        }
        __syncthreads();
    }
    {
        int side = r2 >> 4;
        int bb = b0 + (r2 & 15);
        size_t orow = ((size_t)side * BATCH + bb) * NCLASS;
        #pragma unroll
        for (int j = 0; j < 8; ++j) {
            int c = cs * 8 + j;
            if (c < NCLASS) out[orow + c] = acc2[j];
        }
    }
}

// ---------------------------------------------------------------------------
extern "C" void kernel_launch(void* const* d_in, const int* in_sizes, int n_in,
                              void* d_out, int out_size, void* d_ws, size_t ws_size,
                              hipStream_t stream) {
    const float* mem       = (const float*)d_in[0];
    const float* edge_feat = (const float*)d_in[1];
    const float* Wq        = (const float*)d_in[2];
    const float* Wk        = (const float*)d_in[3];
    const float* a         = (const float*)d_in[4];
    const float* Wew       = (const float*)d_in[5];
    const float* Web       = (const float*)d_in[6];
    const float* Wuc       = (const float*)d_in[7];
    const float* Wc1       = (const float*)d_in[8];
    const float* Wc2       = (const float*)d_in[9];
    const int* src_idxs    = (const int*)d_in[10];
    const int* dst_idxs    = (const int*)d_in[11];
    const int* edge_idxs   = (const int*)d_in[12];
    const int* src_nb      = (const int*)d_in[13];
    const int* dst_nb      = (const int*)d_in[14];
    float* out = (float*)d_out;

    float* ws = (float*)d_ws;
    float* Wcomb2 = ws;                  // 384*128 = 49152
    float* be     = ws + 49152;          // 128
    float* wqa    = ws + 49280;          // 128
    float* wka    = ws + 49408;          // 128
    float* nsq    = ws + 49536;          // 200000
    float* nsk    = ws + 249536;         // 200000
    float* agg    = ws + 449536;         // 2*8192*128 = 2097152

    k_prep<<<50, 256, 0, stream>>>(Wq, Wk, a, Wew, Web, Wuc, wqa, wka, be, Wcomb2);
    k_scores<<<200000 / 64, 256, 0, stream>>>(mem, wqa, wka, nsq, nsk);
    k_attn<<<2 * BATCH / 8, 256, 0, stream>>>(mem, nsq, nsk, src_idxs, dst_idxs,
                                              src_nb, dst_nb, agg);
    k_gemm<<<BATCH / NB, 256, 0, stream>>>(mem, edge_feat, Wuc, Wcomb2, be, agg,
                                           nsq ? Wc1 : Wc1, Wc2,
                                           src_idxs, dst_idxs, edge_idxs, out);
}

// Round 2
// 492.222 us; speedup vs baseline: 1.0179x; 1.0179x over previous
//
#include <hip/hip_runtime.h>

#define D 128
#define KNBR 32
#define BATCH 8192
#define NCLASS 60
#define NB 16      // b rows per block (k_gemm)
#define NP 32      // (b, side) pairs per block (k_gemm)

__device__ __forceinline__ unsigned short f2bf_rne(float f) {
    unsigned int x = __float_as_uint(f);
    x = x + 0x7FFFu + ((x >> 16) & 1u);      // round-to-nearest-even
    return (unsigned short)(x >> 16);
}
__device__ __forceinline__ float bf2f(unsigned short h) {
    return __uint_as_float(((unsigned int)h) << 16);
}

// ---------------------------------------------------------------------------
// K0: prep. blk0: wqa = Wq@a[:D], wka = Wk@a[D:]
//          blk1: be = We_b @ Wuc[384:512]
//          blks 2..49: Wcomb2 = [Wk@Wuc[128:256]; Wk@Wuc[256:384]; We_w@Wuc[384:512]]
__global__ __launch_bounds__(256) void k_prep(
    const float* __restrict__ Wq, const float* __restrict__ Wk,
    const float* __restrict__ a, const float* __restrict__ Wew,
    const float* __restrict__ Web, const float* __restrict__ Wuc,
    float* __restrict__ wqa, float* __restrict__ wka,
    float* __restrict__ be, float* __restrict__ Wcomb2)
{
    __shared__ float sB[128][129];
    int blk = blockIdx.x, tid = threadIdx.x;
    if (blk == 0) {
        for (int t = tid; t < 128 * 128; t += 256) sB[t >> 7][t & 127] = Wq[t];
        __syncthreads();
        if (tid < 128) {
            float s = 0.f;
            for (int j = 0; j < D; ++j) s += sB[tid][j] * a[j];
            wqa[tid] = s;
        }
        __syncthreads();
        for (int t = tid; t < 128 * 128; t += 256) sB[t >> 7][t & 127] = Wk[t];
        __syncthreads();
        if (tid < 128) {
            float s = 0.f;
            for (int j = 0; j < D; ++j) s += sB[tid][j] * a[D + j];
            wka[tid] = s;
        }
    } else if (blk == 1) {
        if (tid < 128) {
            float acc = 0.f;
            for (int j = 0; j < D; ++j) acc += Web[j] * Wuc[(size_t)(384 + j) * D + tid];
            be[tid] = acc;
        }
    } else {
        int g  = (blk - 2) >> 4;
        int rb = ((blk - 2) & 15) * 8;
        const float* A = (g == 2) ? Wew : Wk;
        const float* B = Wuc + (size_t)(128 + g * 128) * D;
        for (int t = tid; t < 128 * 128; t += 256) sB[t >> 7][t & 127] = B[t];
        __syncthreads();
        int j = tid & 127, half = tid >> 7;
        float acc[4] = {0.f, 0.f, 0.f, 0.f};
        int r0 = rb + half * 4;
        for (int t = 0; t < 128; ++t) {
            float bv = sB[t][j];
            #pragma unroll
            for (int m = 0; m < 4; ++m)
                acc[m] = fmaf(A[(size_t)(r0 + m) * D + t], bv, acc[m]);
        }
        #pragma unroll
        for (int m = 0; m < 4; ++m)
            Wcomb2[(size_t)(g * 128 + r0 + m) * D + j] = acc[m];
    }
}

// ---------------------------------------------------------------------------
// K1: per-node scores sq/sk + bf16 conversion of the node table (fused:
// this kernel already streams all of mem once, coalesced).
__global__ __launch_bounds__(256) void k_scores(
    const float* __restrict__ mem,
    const float* __restrict__ wqa, const float* __restrict__ wka,
    float* __restrict__ nsq, float* __restrict__ nsk,
    unsigned short* __restrict__ memh)
{
    int tid = threadIdx.x, lane = tid & 31, grp = tid >> 5;
    int n0 = blockIdx.x * 64 + grp * 8;
    float4 wq4 = ((const float4*)wqa)[lane];
    float4 wk4 = ((const float4*)wka)[lane];
    #pragma unroll
    for (int i = 0; i < 8; ++i) {
        int n = n0 + i;
        float4 v = ((const float4*)(mem + (size_t)n * D))[lane];
        // bf16 copy for the gather kernel (halves bytes/row -> halves misses)
        ushort4 hv;
        hv.x = f2bf_rne(v.x); hv.y = f2bf_rne(v.y);
        hv.z = f2bf_rne(v.z); hv.w = f2bf_rne(v.w);
        ((ushort4*)(memh + (size_t)n * D))[lane] = hv;

        float pq = v.x * wq4.x + v.y * wq4.y + v.z * wq4.z + v.w * wq4.w;
        float pk = v.x * wk4.x + v.y * wk4.y + v.z * wk4.z + v.w * wk4.w;
        #pragma unroll
        for (int m = 1; m <= 16; m <<= 1) {
            pq += __shfl_xor(pq, m, 32);
            pk += __shfl_xor(pk, m, 32);
        }
        if (lane == 0) nsq[n] = pq;
        if (lane == 1) nsk[n] = pk;
    }
}

// ---------------------------------------------------------------------------
// K2a: attention + weighted neighbor gather from the bf16 table. One 32-lane
// group per (b,side) pair; rows are 256 B (4 cache lines) instead of 512 B,
// doubling the rows/outstanding-miss-budget. No LDS, no barriers.
__global__ __launch_bounds__(256) void k_attn(
    const unsigned short* __restrict__ memh,
    const float* __restrict__ nsq, const float* __restrict__ nsk,
    const int* __restrict__ src_idxs, const int* __restrict__ dst_idxs,
    const int* __restrict__ src_nb, const int* __restrict__ dst_nb,
    float* __restrict__ agg)
{
    int lane = threadIdx.x & 31;
    int grp  = threadIdx.x >> 5;
    int p    = blockIdx.x * 8 + grp;          // 0 .. 2*BATCH-1
    int side = p >> 13;                        // BATCH = 8192
    int b    = p & (BATCH - 1);

    int self_idx = (side ? dst_idxs : src_idxs)[b];
    int ik = (side ? dst_nb : src_nb)[(size_t)b * KNBR + lane];

    float x = nsq[self_idx] + nsk[ik];
    x = (x >= 0.f) ? x : 0.2f * x;             // leaky_relu(0.2)
    float mx = x;
    #pragma unroll
    for (int m = 1; m <= 16; m <<= 1) mx = fmaxf(mx, __shfl_xor(mx, m, 32));
    float e = __expf(x - mx);
    float s = e;
    #pragma unroll
    for (int m = 1; m <= 16; m <<= 1) s += __shfl_xor(s, m, 32);
    float attn = e / s;

    float4 acc = make_float4(0.f, 0.f, 0.f, 0.f);
    #pragma unroll 16
    for (int k = 0; k < KNBR; ++k) {
        int   ikk = __shfl(ik, k, 32);
        float ak  = __shfl(attn, k, 32);
        ushort4 hv = ((const ushort4*)(memh + (size_t)ikk * D))[lane];
        acc.x = fmaf(ak, bf2f(hv.x), acc.x);
        acc.y = fmaf(ak, bf2f(hv.y), acc.y);
        acc.z = fmaf(ak, bf2f(hv.z), acc.z);
        acc.w = fmaf(ak, bf2f(hv.w), acc.w);
    }
    ((float4*)(agg + (size_t)p * D))[lane] = acc;
}

// ---------------------------------------------------------------------------
// K2b: msg + cls GEMMs. 16 b's x 2 sides per block. agg staged coalesced from
// workspace into the transposed LDS layout the GEMM consumes.
__global__ __launch_bounds__(256, 3) void k_gemm(
    const float* __restrict__ mem, const float* __restrict__ edge_feat,
    const float* __restrict__ Wuc, const float* __restrict__ Wcomb2,
    const float* __restrict__ be, const float* __restrict__ agg,
    const float* __restrict__ Wc1, const float* __restrict__ Wc2,
    const int* __restrict__ src_idxs, const int* __restrict__ dst_idxs,
    const int* __restrict__ edge_idxs,
    float* __restrict__ out)
{
    __shared__ __align__(16) float Ws[32 * 128];     // 16384 B
    __shared__ __align__(16) float nbT[128 * 33];    // 16896 B  [col][pair]
    __shared__ __align__(16) float uni[128 * 33];    // 16896 B  Ast (32x33) / msgT (128x33)
    __shared__ int s_sidx[NP];
    __shared__ int s_eidx[NB];

    int tid = threadIdx.x;
    int b0 = blockIdx.x * NB;
    int lane = tid & 31;
    int grp  = tid >> 5;

    if (tid < NP) s_sidx[tid] = ((tid >> 4) ? dst_idxs : src_idxs)[b0 + (tid & 15)];
    if (tid < NB) s_eidx[tid] = edge_idxs[b0 + tid];

    // ---------------- stage aggT from workspace (coalesced), transposed
    #pragma unroll
    for (int q = 0; q < 4; ++q) {
        int pp = grp + 8 * q;                              // 0..31
        int gp = ((pp >> 4) ? BATCH : 0) + b0 + (pp & 15); // global pair id
        float4 v = ((const float4*)(agg + (size_t)gp * D))[lane];
        nbT[(lane * 4 + 0) * 33 + pp] = v.x;
        nbT[(lane * 4 + 1) * 33 + pp] = v.y;
        nbT[(lane * 4 + 2) * 33 + pp] = v.z;
        nbT[(lane * 4 + 3) * 33 + pp] = v.w;
    }
    __syncthreads();

    // ---------------- Phase B: msg = relu(A @ [Wuc; Wcomb2] + be), A = [32 x 512]
    int tr = tid >> 4, tc = tid & 15;          // 16x16 micro grid, 2 rows x 8 cols
    int lc = tid & 31, lr = tid >> 5;          // A staging lanes
    int wc = tid & 127, wk2 = tid >> 7;        // W staging lanes
    float accB[2][8];
    #pragma unroll
    for (int i = 0; i < 2; ++i)
        #pragma unroll
        for (int j = 0; j < 8; ++j) accB[i][j] = 0.f;

    float* Ast = uni;

    // seg 0 (kt 0..3): A = self rows, staged from mem
    for (int kt = 0; kt < 4; ++kt) {
        int off = kt * 32;
        #pragma unroll
        for (int q = 0; q < 4; ++q) {
            int r = lr + 8 * q;
            Ast[lc * 33 + r] = mem[(size_t)s_sidx[r] * D + off + lc];
        }
        #pragma unroll
        for (int pp = 0; pp < 16; ++pp) {
            int kk = wk2 + 2 * pp;
            Ws[kk * 128 + wc] = Wuc[(size_t)(off + kk) * D + wc];
        }
        __syncthreads();
        #pragma unroll 8
        for (int kk = 0; kk < 32; ++kk) {
            float a0 = Ast[kk * 33 + tr * 2];
            float a1 = Ast[kk * 33 + tr * 2 + 1];
            float4 w0 = *(const float4*)&Ws[kk * 128 + tc * 4];
            float4 w1 = *(const float4*)&Ws[kk * 128 + 64 + tc * 4];
            float wr[8] = {w0.x, w0.y, w0.z, w0.w, w1.x, w1.y, w1.z, w1.w};
            #pragma unroll
            for (int j = 0; j < 8; ++j) {
                accB[0][j] = fmaf(a0, wr[j], accB[0][j]);
                accB[1][j] = fmaf(a1, wr[j], accB[1][j]);
            }
        }
        __syncthreads();
    }
    // segs 1-2 (kt 4..11): A read directly from nbT (no staging)
    for (int kt = 4; kt < 12; ++kt) {
        int off = (kt & 3) * 32;
        int gr0 = kt * 32 - 128;
        #pragma unroll
        for (int pp = 0; pp < 16; ++pp) {
            int kk = wk2 + 2 * pp;
            Ws[kk * 128 + wc] = Wcomb2[(size_t)(gr0 + kk) * D + wc];
        }
        __syncthreads();
        int r0 = (kt < 8) ? (tr * 2) : ((tr * 2) ^ 16);
        #pragma unroll 8
        for (int kk = 0; kk < 32; ++kk) {
            float a0 = nbT[(off + kk) * 33 + r0];
            float a1 = nbT[(off + kk) * 33 + r0 + 1];
            float4 w0 = *(const float4*)&Ws[kk * 128 + tc * 4];
            float4 w1 = *(const float4*)&Ws[kk * 128 + 64 + tc * 4];
            float wr[8] = {w0.x, w0.y, w0.z, w0.w, w1.x, w1.y, w1.z, w1.w};
            #pragma unroll
            for (int j = 0; j < 8; ++j) {
                accB[0][j] = fmaf(a0, wr[j], accB[0][j]);
                accB[1][j] = fmaf(a1, wr[j], accB[1][j]);
            }
        }
        __syncthreads();
    }
    // seg 3 (kt 12..15): A = edge rows, staged from edge_feat
    for (int kt = 12; kt < 16; ++kt) {
        int off = (kt & 3) * 32;
        int gr0 = kt * 32 - 128;
        #pragma unroll
        for (int q = 0; q < 4; ++q) {
            int r = lr + 8 * q;
            Ast[lc * 33 + r] = edge_feat[(size_t)s_eidx[r & 15] * D + off + lc];
        }
        #pragma unroll
        for (int pp = 0; pp < 16; ++pp) {
            int kk = wk2 + 2 * pp;
            Ws[kk * 128 + wc] = Wcomb2[(size_t)(gr0 + kk) * D + wc];
        }
        __syncthreads();
        #pragma unroll 8
        for (int kk = 0; kk < 32; ++kk) {
            float a0 = Ast[kk * 33 + tr * 2];
            float a1 = Ast[kk * 33 + tr * 2 + 1];
            float4 w0 = *(const float4*)&Ws[kk * 128 + tc * 4];
            float4 w1 = *(const float4*)&Ws[kk * 128 + 64 + tc * 4];
            float wr[8] = {w0.x, w0.y, w0.z, w0.w, w1.x, w1.y, w1.z, w1.w};
            #pragma unroll
            for (int j = 0; j < 8; ++j) {
                accB[0][j] = fmaf(a0, wr[j], accB[0][j]);
                accB[1][j] = fmaf(a1, wr[j], accB[1][j]);
            }
        }
        __syncthreads();
    }

    // bias + relu -> msgT[col][row]  (uni: Ast is dead, last read was pre-sync)
    float* msgT = uni;
    {
        float4 bv0 = *(const float4*)&be[tc * 4];
        float4 bv1 = *(const float4*)&be[64 + tc * 4];
        float b8[8] = {bv0.x, bv0.y, bv0.z, bv0.w, bv1.x, bv1.y, bv1.z, bv1.w};
        #pragma unroll
        for (int i = 0; i < 2; ++i) {
            int r = tr * 2 + i;
            #pragma unroll
            for (int j = 0; j < 4; ++j) {
                msgT[(tc * 4 + j) * 33 + r]      = fmaxf(accB[i][j] + b8[j], 0.f);
                msgT[(64 + tc * 4 + j) * 33 + r] = fmaxf(accB[i][j + 4] + b8[j + 4], 0.f);
            }
        }
    }
    __syncthreads();

    // ---------------- Phase C: GEMM1 h1 = relu(msg @ Wc1)
    float accC[2][8];
    #pragma unroll
    for (int i = 0; i < 2; ++i)
        #pragma unroll
        for (int j = 0; j < 8; ++j) accC[i][j] = 0.f;

    for (int kt = 0; kt < 4; ++kt) {
        int off = kt * 32;
        #pragma unroll
        for (int pp = 0; pp < 16; ++pp) {
            int kk = wk2 + 2 * pp;
            Ws[kk * 128 + wc] = Wc1[(size_t)(off + kk) * D + wc];
        }
        __syncthreads();
        #pragma unroll 8
        for (int kk = 0; kk < 32; ++kk) {
            float a0 = msgT[(off + kk) * 33 + tr * 2];
            float a1 = msgT[(off + kk) * 33 + tr * 2 + 1];
            float4 w0 = *(const float4*)&Ws[kk * 128 + tc * 4];
            float4 w1 = *(const float4*)&Ws[kk * 128 + 64 + tc * 4];
            float wr[8] = {w0.x, w0.y, w0.z, w0.w, w1.x, w1.y, w1.z, w1.w};
            #pragma unroll
            for (int j = 0; j < 8; ++j) {
                accC[0][j] = fmaf(a0, wr[j], accC[0][j]);
                accC[1][j] = fmaf(a1, wr[j], accC[1][j]);
            }
        }
        __syncthreads();
    }
    // relu -> h1T overwrites msgT
    #pragma unroll
    for (int i = 0; i < 2; ++i) {
        int r = tr * 2 + i;
        #pragma unroll
        for (int j = 0; j < 4; ++j) {
            msgT[(tc * 4 + j) * 33 + r]      = fmaxf(accC[i][j], 0.f);
            msgT[(64 + tc * 4 + j) * 33 + r] = fmaxf(accC[i][j + 4], 0.f);
        }
    }
    __syncthreads();

    // ---------------- Phase C: GEMM2 logits = h1 @ Wc2  [32x128]@[128x60]
    int r2 = tid & 31;
    int cs = tid >> 5;
    float acc2[8];
    #pragma unroll
    for (int j = 0; j < 8; ++j) acc2[j] = 0.f;

    for (int kt = 0; kt < 4; ++kt) {
        int off = kt * 32;
        for (int t = tid; t < 32 * 64; t += 256) {
            int kk = t >> 6, c = t & 63;
            Ws[t] = (c < NCLASS) ? Wc2[(size_t)(off + kk) * NCLASS + c] : 0.f;
        }
        __syncthreads();
        #pragma unroll 4
        for (int kk = 0; kk < 32; ++kk) {
            float h = msgT[(off + kk) * 33 + r2];
            float4 w0 = *(const float4*)&Ws[kk * 64 + cs * 8];
            float4 w1 = *(const float4*)&Ws[kk * 64 + cs * 8 + 4];
            acc2[0] = fmaf(h, w0.x, acc2[0]);
            acc2[1] = fmaf(h, w0.y, acc2[1]);
            acc2[2] = fmaf(h, w0.z, acc2[2]);
            acc2[3] = fmaf(h, w0.w, acc2[3]);
            acc2[4] = fmaf(h, w1.x, acc2[4]);
            acc2[5] = fmaf(h, w1.y, acc2[5]);
            acc2[6] = fmaf(h, w1.z, acc2[6]);
            acc2[7] = fmaf(h, w1.w, acc2[7]);
        }
        __syncthreads();
    }
    {
        int side = r2 >> 4;
        int bb = b0 + (r2 & 15);
        size_t orow = ((size_t)side * BATCH + bb) * NCLASS;
        #pragma unroll
        for (int j = 0; j < 8; ++j) {
            int c = cs * 8 + j;
            if (c < NCLASS) out[orow + c] = acc2[j];
        }
    }
}

// ---------------------------------------------------------------------------
extern "C" void kernel_launch(void* const* d_in, const int* in_sizes, int n_in,
                              void* d_out, int out_size, void* d_ws, size_t ws_size,
                              hipStream_t stream) {
    const float* mem       = (const float*)d_in[0];
    const float* edge_feat = (const float*)d_in[1];
    const float* Wq        = (const float*)d_in[2];
    const float* Wk        = (const float*)d_in[3];
    const float* a         = (const float*)d_in[4];
    const float* Wew       = (const float*)d_in[5];
    const float* Web       = (const float*)d_in[6];
    const float* Wuc       = (const float*)d_in[7];
    const float* Wc1       = (const float*)d_in[8];
    const float* Wc2       = (const float*)d_in[9];
    const int* src_idxs    = (const int*)d_in[10];
    const int* dst_idxs    = (const int*)d_in[11];
    const int* edge_idxs   = (const int*)d_in[12];
    const int* src_nb      = (const int*)d_in[13];
    const int* dst_nb      = (const int*)d_in[14];
    float* out = (float*)d_out;

    float* ws = (float*)d_ws;
    float* Wcomb2 = ws;                  // 384*128 = 49152
    float* be     = ws + 49152;          // 128
    float* wqa    = ws + 49280;          // 128
    float* wka    = ws + 49408;          // 128
    float* nsq    = ws + 49536;          // 200000
    float* nsk    = ws + 249536;         // 200000
    float* agg    = ws + 449536;         // 2*8192*128 = 2097152
    unsigned short* memh = (unsigned short*)(ws + 2546688);  // 200000*128 bf16 = 51.2 MB

    k_prep<<<50, 256, 0, stream>>>(Wq, Wk, a, Wew, Web, Wuc, wqa, wka, be, Wcomb2);
    k_scores<<<200000 / 64, 256, 0, stream>>>(mem, wqa, wka, nsq, nsk, memh);
    k_attn<<<2 * BATCH / 8, 256, 0, stream>>>(memh, nsq, nsk, src_idxs, dst_idxs,
                                              src_nb, dst_nb, agg);
    k_gemm<<<BATCH / NB, 256, 0, stream>>>(mem, edge_feat, Wuc, Wcomb2, be, agg,
                                           Wc1, Wc2,
                                           src_idxs, dst_idxs, edge_idxs, out);
}

// Round 3
// 491.960 us; speedup vs baseline: 1.0185x; 1.0005x over previous
//
#include <hip/hip_runtime.h>

#define D 128
#define KNBR 32
#define BATCH 8192
#define NCLASS 60
#define NB 16      // b rows per block (k_gemm)
#define NP 32      // (b, side) pairs per block (k_gemm)

__device__ __forceinline__ unsigned short f2bf_rne(float f) {
    unsigned int x = __float_as_uint(f);
    x = x + 0x7FFFu + ((x >> 16) & 1u);      // round-to-nearest-even
    return (unsigned short)(x >> 16);
}

// ---------------------------------------------------------------------------
// K0: prep. blk0: wqa = Wq@a[:D], wka = Wk@a[D:]
//          blk1: be = We_b @ Wuc[384:512]
//          blks 2..49: Wcomb2 = [Wk@Wuc[128:256]; Wk@Wuc[256:384]; We_w@Wuc[384:512]]
__global__ __launch_bounds__(256) void k_prep(
    const float* __restrict__ Wq, const float* __restrict__ Wk,
    const float* __restrict__ a, const float* __restrict__ Wew,
    const float* __restrict__ Web, const float* __restrict__ Wuc,
    float* __restrict__ wqa, float* __restrict__ wka,
    float* __restrict__ be, float* __restrict__ Wcomb2)
{
    __shared__ float sB[128][129];
    int blk = blockIdx.x, tid = threadIdx.x;
    if (blk == 0) {
        for (int t = tid; t < 128 * 128; t += 256) sB[t >> 7][t & 127] = Wq[t];
        __syncthreads();
        if (tid < 128) {
            float s = 0.f;
            for (int j = 0; j < D; ++j) s += sB[tid][j] * a[j];
            wqa[tid] = s;
        }
        __syncthreads();
        for (int t = tid; t < 128 * 128; t += 256) sB[t >> 7][t & 127] = Wk[t];
        __syncthreads();
        if (tid < 128) {
            float s = 0.f;
            for (int j = 0; j < D; ++j) s += sB[tid][j] * a[D + j];
            wka[tid] = s;
        }
    } else if (blk == 1) {
        if (tid < 128) {
            float acc = 0.f;
            for (int j = 0; j < D; ++j) acc += Web[j] * Wuc[(size_t)(384 + j) * D + tid];
            be[tid] = acc;
        }
    } else {
        int g  = (blk - 2) >> 4;
        int rb = ((blk - 2) & 15) * 8;
        const float* A = (g == 2) ? Wew : Wk;
        const float* B = Wuc + (size_t)(128 + g * 128) * D;
        for (int t = tid; t < 128 * 128; t += 256) sB[t >> 7][t & 127] = B[t];
        __syncthreads();
        int j = tid & 127, half = tid >> 7;
        float acc[4] = {0.f, 0.f, 0.f, 0.f};
        int r0 = rb + half * 4;
        for (int t = 0; t < 128; ++t) {
            float bv = sB[t][j];
            #pragma unroll
            for (int m = 0; m < 4; ++m)
                acc[m] = fmaf(A[(size_t)(r0 + m) * D + t], bv, acc[m]);
        }
        #pragma unroll
        for (int m = 0; m < 4; ++m)
            Wcomb2[(size_t)(g * 128 + r0 + m) * D + j] = acc[m];
    }
}

// ---------------------------------------------------------------------------
// K1: per-node scores sq/sk + bf16 conversion of the node table (fused:
// this kernel already streams all of mem once, coalesced).
__global__ __launch_bounds__(256) void k_scores(
    const float* __restrict__ mem,
    const float* __restrict__ wqa, const float* __restrict__ wka,
    float* __restrict__ nsq, float* __restrict__ nsk,
    unsigned short* __restrict__ memh)
{
    int tid = threadIdx.x, lane = tid & 31, grp = tid >> 5;
    int n0 = blockIdx.x * 64 + grp * 8;
    float4 wq4 = ((const float4*)wqa)[lane];
    float4 wk4 = ((const float4*)wka)[lane];
    #pragma unroll
    for (int i = 0; i < 8; ++i) {
        int n = n0 + i;
        float4 v = ((const float4*)(mem + (size_t)n * D))[lane];
        // bf16 copy for the gather kernel
        ushort4 hv;
        hv.x = f2bf_rne(v.x); hv.y = f2bf_rne(v.y);
        hv.z = f2bf_rne(v.z); hv.w = f2bf_rne(v.w);
        ((ushort4*)(memh + (size_t)n * D))[lane] = hv;

        float pq = v.x * wq4.x + v.y * wq4.y + v.z * wq4.z + v.w * wq4.w;
        float pk = v.x * wk4.x + v.y * wk4.y + v.z * wk4.z + v.w * wk4.w;
        #pragma unroll
        for (int m = 1; m <= 16; m <<= 1) {
            pq += __shfl_xor(pq, m, 32);
            pk += __shfl_xor(pk, m, 32);
        }
        if (lane == 0) nsq[n] = pq;
        if (lane == 1) nsk[n] = pk;
    }
}

// ---------------------------------------------------------------------------
// K2a: attention + weighted neighbor gather. ONE WAVE64 PER PAIR; each lane
// loads uint4 = 8 bf16 (16 B), so one wave instruction covers 4 rows (1 KB)
// and a pair's 32 rows take 8 VMEM instructions (vs 16 before) — the gather
// is outstanding-VMEM-INSTRUCTION bound, so instructions are the currency.
// lane = (rsub = lane>>4: row subset k%4, lr = lane&15: dims [lr*8, lr*8+8)).
// Softmax is computed redundantly in both wave halves (same ik loaded).
__global__ __launch_bounds__(256) void k_attn(
    const unsigned short* __restrict__ memh,
    const float* __restrict__ nsq, const float* __restrict__ nsk,
    const int* __restrict__ src_idxs, const int* __restrict__ dst_idxs,
    const int* __restrict__ src_nb, const int* __restrict__ dst_nb,
    float* __restrict__ agg)
{
    int lane = threadIdx.x & 63;
    int wid  = threadIdx.x >> 6;
    int p    = blockIdx.x * 4 + wid;           // one pair per wave
    int side = p >> 13;                         // BATCH = 8192
    int b    = p & (BATCH - 1);

    int self_idx = (side ? dst_idxs : src_idxs)[b];
    int ik = (side ? dst_nb : src_nb)[(size_t)b * KNBR + (lane & 31)];

    float x = nsq[self_idx] + nsk[ik];
    x = (x >= 0.f) ? x : 0.2f * x;             // leaky_relu(0.2)
    float mx = x;
    #pragma unroll
    for (int m = 1; m <= 16; m <<= 1) mx = fmaxf(mx, __shfl_xor(mx, m, 32));
    float e = __expf(x - mx);
    float s = e;
    #pragma unroll
    for (int m = 1; m <= 16; m <<= 1) s += __shfl_xor(s, m, 32);
    float attn = e / s;                        // valid in both halves

    int rsub = lane >> 4;                      // 0..3
    int lr   = lane & 15;                      // dim slice

    float acc[8];
    #pragma unroll
    for (int j = 0; j < 8; ++j) acc[j] = 0.f;

    #pragma unroll
    for (int k0 = 0; k0 < KNBR; k0 += 4) {
        int   k   = k0 + rsub;
        int   ikk = __shfl(ik, k, 64);         // ik lives in lanes 0..31
        float ak  = __shfl(attn, k, 64);
        uint4 hv = *(const uint4*)(memh + (size_t)ikk * D + lr * 8);
        acc[0] = fmaf(ak, __uint_as_float(hv.x << 16),          acc[0]);
        acc[1] = fmaf(ak, __uint_as_float(hv.x & 0xFFFF0000u),  acc[1]);
        acc[2] = fmaf(ak, __uint_as_float(hv.y << 16),          acc[2]);
        acc[3] = fmaf(ak, __uint_as_float(hv.y & 0xFFFF0000u),  acc[3]);
        acc[4] = fmaf(ak, __uint_as_float(hv.z << 16),          acc[4]);
        acc[5] = fmaf(ak, __uint_as_float(hv.z & 0xFFFF0000u),  acc[5]);
        acc[6] = fmaf(ak, __uint_as_float(hv.w << 16),          acc[6]);
        acc[7] = fmaf(ak, __uint_as_float(hv.w & 0xFFFF0000u),  acc[7]);
    }
    // fold the 4 row-subsets (lanes lr, lr+16, lr+32, lr+48)
    #pragma unroll
    for (int j = 0; j < 8; ++j) {
        acc[j] += __shfl_xor(acc[j], 16, 64);
        acc[j] += __shfl_xor(acc[j], 32, 64);
    }
    float* orow = agg + (size_t)p * D + lr * 8;
    if (rsub == 0) *(float4*)orow       = make_float4(acc[0], acc[1], acc[2], acc[3]);
    if (rsub == 1) *(float4*)(orow + 4) = make_float4(acc[4], acc[5], acc[6], acc[7]);
}

// ---------------------------------------------------------------------------
// K2b: msg + cls GEMMs. 16 b's x 2 sides per block. agg staged coalesced from
// workspace into the transposed LDS layout the GEMM consumes.
__global__ __launch_bounds__(256, 3) void k_gemm(
    const float* __restrict__ mem, const float* __restrict__ edge_feat,
    const float* __restrict__ Wuc, const float* __restrict__ Wcomb2,
    const float* __restrict__ be, const float* __restrict__ agg,
    const float* __restrict__ Wc1, const float* __restrict__ Wc2,
    const int* __restrict__ src_idxs, const int* __restrict__ dst_idxs,
    const int* __restrict__ edge_idxs,
    float* __restrict__ out)
{
    __shared__ __align__(16) float Ws[32 * 128];     // 16384 B
    __shared__ __align__(16) float nbT[128 * 33];    // 16896 B  [col][pair]
    __shared__ __align__(16) float uni[128 * 33];    // 16896 B  Ast (32x33) / msgT (128x33)
    __shared__ int s_sidx[NP];
    __shared__ int s_eidx[NB];

    int tid = threadIdx.x;
    int b0 = blockIdx.x * NB;
    int lane = tid & 31;
    int grp  = tid >> 5;

    if (tid < NP) s_sidx[tid] = ((tid >> 4) ? dst_idxs : src_idxs)[b0 + (tid & 15)];
    if (tid < NB) s_eidx[tid] = edge_idxs[b0 + tid];

    // ---------------- stage aggT from workspace (coalesced), transposed
    #pragma unroll
    for (int q = 0; q < 4; ++q) {
        int pp = grp + 8 * q;                              // 0..31
        int gp = ((pp >> 4) ? BATCH : 0) + b0 + (pp & 15); // global pair id
        float4 v = ((const float4*)(agg + (size_t)gp * D))[lane];
        nbT[(lane * 4 + 0) * 33 + pp] = v.x;
        nbT[(lane * 4 + 1) * 33 + pp] = v.y;
        nbT[(lane * 4 + 2) * 33 + pp] = v.z;
        nbT[(lane * 4 + 3) * 33 + pp] = v.w;
    }
    __syncthreads();

    // ---------------- Phase B: msg = relu(A @ [Wuc; Wcomb2] + be), A = [32 x 512]
    int tr = tid >> 4, tc = tid & 15;          // 16x16 micro grid, 2 rows x 8 cols
    int lc = tid & 31, lr = tid >> 5;          // A staging lanes
    int wc = tid & 127, wk2 = tid >> 7;        // W staging lanes
    float accB[2][8];
    #pragma unroll
    for (int i = 0; i < 2; ++i)
        #pragma unroll
        for (int j = 0; j < 8; ++j) accB[i][j] = 0.f;

    float* Ast = uni;

    // seg 0 (kt 0..3): A = self rows, staged from mem
    for (int kt = 0; kt < 4; ++kt) {
        int off = kt * 32;
        #pragma unroll
        for (int q = 0; q < 4; ++q) {
            int r = lr + 8 * q;
            Ast[lc * 33 + r] = mem[(size_t)s_sidx[r] * D + off + lc];
        }
        #pragma unroll
        for (int pp = 0; pp < 16; ++pp) {
            int kk = wk2 + 2 * pp;
            Ws[kk * 128 + wc] = Wuc[(size_t)(off + kk) * D + wc];
        }
        __syncthreads();
        #pragma unroll 8
        for (int kk = 0; kk < 32; ++kk) {
            float a0 = Ast[kk * 33 + tr * 2];
            float a1 = Ast[kk * 33 + tr * 2 + 1];
            float4 w0 = *(const float4*)&Ws[kk * 128 + tc * 4];
            float4 w1 = *(const float4*)&Ws[kk * 128 + 64 + tc * 4];
            float wr[8] = {w0.x, w0.y, w0.z, w0.w, w1.x, w1.y, w1.z, w1.w};
            #pragma unroll
            for (int j = 0; j < 8; ++j) {
                accB[0][j] = fmaf(a0, wr[j], accB[0][j]);
                accB[1][j] = fmaf(a1, wr[j], accB[1][j]);
            }
        }
        __syncthreads();
    }
    // segs 1-2 (kt 4..11): A read directly from nbT (no staging)
    for (int kt = 4; kt < 12; ++kt) {
        int off = (kt & 3) * 32;
        int gr0 = kt * 32 - 128;
        #pragma unroll
        for (int pp = 0; pp < 16; ++pp) {
            int kk = wk2 + 2 * pp;
            Ws[kk * 128 + wc] = Wcomb2[(size_t)(gr0 + kk) * D + wc];
        }
        __syncthreads();
        int r0 = (kt < 8) ? (tr * 2) : ((tr * 2) ^ 16);
        #pragma unroll 8
        for (int kk = 0; kk < 32; ++kk) {
            float a0 = nbT[(off + kk) * 33 + r0];
            float a1 = nbT[(off + kk) * 33 + r0 + 1];
            float4 w0 = *(const float4*)&Ws[kk * 128 + tc * 4];
            float4 w1 = *(const float4*)&Ws[kk * 128 + 64 + tc * 4];
            float wr[8] = {w0.x, w0.y, w0.z, w0.w, w1.x, w1.y, w1.z, w1.w};
            #pragma unroll
            for (int j = 0; j < 8; ++j) {
                accB[0][j] = fmaf(a0, wr[j], accB[0][j]);
                accB[1][j] = fmaf(a1, wr[j], accB[1][j]);
            }
        }
        __syncthreads();
    }
    // seg 3 (kt 12..15): A = edge rows, staged from edge_feat
    for (int kt = 12; kt < 16; ++kt) {
        int off = (kt & 3) * 32;
        int gr0 = kt * 32 - 128;
        #pragma unroll
        for (int q = 0; q < 4; ++q) {
            int r = lr + 8 * q;
            Ast[lc * 33 + r] = edge_feat[(size_t)s_eidx[r & 15] * D + off + lc];
        }
        #pragma unroll
        for (int pp = 0; pp < 16; ++pp) {
            int kk = wk2 + 2 * pp;
            Ws[kk * 128 + wc] = Wcomb2[(size_t)(gr0 + kk) * D + wc];
        }
        __syncthreads();
        #pragma unroll 8
        for (int kk = 0; kk < 32; ++kk) {
            float a0 = Ast[kk * 33 + tr * 2];
            float a1 = Ast[kk * 33 + tr * 2 + 1];
            float4 w0 = *(const float4*)&Ws[kk * 128 + tc * 4];
            float4 w1 = *(const float4*)&Ws[kk * 128 + 64 + tc * 4];
            float wr[8] = {w0.x, w0.y, w0.z, w0.w, w1.x, w1.y, w1.z, w1.w};
            #pragma unroll
            for (int j = 0; j < 8; ++j) {
                accB[0][j] = fmaf(a0, wr[j], accB[0][j]);
                accB[1][j] = fmaf(a1, wr[j], accB[1][j]);
            }
        }
        __syncthreads();
    }

    // bias + relu -> msgT[col][row]  (uni: Ast is dead, last read was pre-sync)
    float* msgT = uni;
    {
        float4 bv0 = *(const float4*)&be[tc * 4];
        float4 bv1 = *(const float4*)&be[64 + tc * 4];
        float b8[8] = {bv0.x, bv0.y, bv0.z, bv0.w, bv1.x, bv1.y, bv1.z, bv1.w};
        #pragma unroll
        for (int i = 0; i < 2; ++i) {
            int r = tr * 2 + i;
            #pragma unroll
            for (int j = 0; j < 4; ++j) {
                msgT[(tc * 4 + j) * 33 + r]      = fmaxf(accB[i][j] + b8[j], 0.f);
                msgT[(64 + tc * 4 + j) * 33 + r] = fmaxf(accB[i][j + 4] + b8[j + 4], 0.f);
            }
        }
    }
    __syncthreads();

    // ---------------- Phase C: GEMM1 h1 = relu(msg @ Wc1)
    float accC[2][8];
    #pragma unroll
    for (int i = 0; i < 2; ++i)
        #pragma unroll
        for (int j = 0; j < 8; ++j) accC[i][j] = 0.f;

    for (int kt = 0; kt < 4; ++kt) {
        int off = kt * 32;
        #pragma unroll
        for (int pp = 0; pp < 16; ++pp) {
            int kk = wk2 + 2 * pp;
            Ws[kk * 128 + wc] = Wc1[(size_t)(off + kk) * D + wc];
        }
        __syncthreads();
        #pragma unroll 8
        for (int kk = 0; kk < 32; ++kk) {
            float a0 = msgT[(off + kk) * 33 + tr * 2];
            float a1 = msgT[(off + kk) * 33 + tr * 2 + 1];
            float4 w0 = *(const float4*)&Ws[kk * 128 + tc * 4];
            float4 w1 = *(const float4*)&Ws[kk * 128 + 64 + tc * 4];
            float wr[8] = {w0.x, w0.y, w0.z, w0.w, w1.x, w1.y, w1.z, w1.w};
            #pragma unroll
            for (int j = 0; j < 8; ++j) {
                accC[0][j] = fmaf(a0, wr[j], accC[0][j]);
                accC[1][j] = fmaf(a1, wr[j], accC[1][j]);
            }
        }
        __syncthreads();
    }
    // relu -> h1T overwrites msgT
    #pragma unroll
    for (int i = 0; i < 2; ++i) {
        int r = tr * 2 + i;
        #pragma unroll
        for (int j = 0; j < 4; ++j) {
            msgT[(tc * 4 + j) * 33 + r]      = fmaxf(accC[i][j], 0.f);
            msgT[(64 + tc * 4 + j) * 33 + r] = fmaxf(accC[i][j + 4], 0.f);
        }
    }
    __syncthreads();

    // ---------------- Phase C: GEMM2 logits = h1 @ Wc2  [32x128]@[128x60]
    int r2 = tid & 31;
    int cs = tid >> 5;
    float acc2[8];
    #pragma unroll
    for (int j = 0; j < 8; ++j) acc2[j] = 0.f;

    for (int kt = 0; kt < 4; ++kt) {
        int off = kt * 32;
        for (int t = tid; t < 32 * 64; t += 256) {
            int kk = t >> 6, c = t & 63;
            Ws[t] = (c < NCLASS) ? Wc2[(size_t)(off + kk) * NCLASS + c] : 0.f;
        }
        __syncthreads();
        #pragma unroll 4
        for (int kk = 0; kk < 32; ++kk) {
            float h = msgT[(off + kk) * 33 + r2];
            float4 w0 = *(const float4*)&Ws[kk * 64 + cs * 8];
            float4 w1 = *(const float4*)&Ws[kk * 64 + cs * 8 + 4];
            acc2[0] = fmaf(h, w0.x, acc2[0]);
            acc2[1] = fmaf(h, w0.y, acc2[1]);
            acc2[2] = fmaf(h, w0.z, acc2[2]);
            acc2[3] = fmaf(h, w0.w, acc2[3]);
            acc2[4] = fmaf(h, w1.x, acc2[4]);
            acc2[5] = fmaf(h, w1.y, acc2[5]);
            acc2[6] = fmaf(h, w1.z, acc2[6]);
            acc2[7] = fmaf(h, w1.w, acc2[7]);
        }
        __syncthreads();
    }
    {
        int side = r2 >> 4;
        int bb = b0 + (r2 & 15);
        size_t orow = ((size_t)side * BATCH + bb) * NCLASS;
        #pragma unroll
        for (int j = 0; j < 8; ++j) {
            int c = cs * 8 + j;
            if (c < NCLASS) out[orow + c] = acc2[j];
        }
    }
}

// ---------------------------------------------------------------------------
extern "C" void kernel_launch(void* const* d_in, const int* in_sizes, int n_in,
                              void* d_out, int out_size, void* d_ws, size_t ws_size,
                              hipStream_t stream) {
    const float* mem       = (const float*)d_in[0];
    const float* edge_feat = (const float*)d_in[1];
    const float* Wq        = (const float*)d_in[2];
    const float* Wk        = (const float*)d_in[3];
    const float* a         = (const float*)d_in[4];
    const float* Wew       = (const float*)d_in[5];
    const float* Web       = (const float*)d_in[6];
    const float* Wuc       = (const float*)d_in[7];
    const float* Wc1       = (const float*)d_in[8];
    const float* Wc2       = (const float*)d_in[9];
    const int* src_idxs    = (const int*)d_in[10];
    const int* dst_idxs    = (const int*)d_in[11];
    const int* edge_idxs   = (const int*)d_in[12];
    const int* src_nb      = (const int*)d_in[13];
    const int* dst_nb      = (const int*)d_in[14];
    float* out = (float*)d_out;

    float* ws = (float*)d_ws;
    float* Wcomb2 = ws;                  // 384*128 = 49152
    float* be     = ws + 49152;          // 128
    float* wqa    = ws + 49280;          // 128
    float* wka    = ws + 49408;          // 128
    float* nsq    = ws + 49536;          // 200000
    float* nsk    = ws + 249536;         // 200000
    float* agg    = ws + 449536;         // 2*8192*128 = 2097152
    unsigned short* memh = (unsigned short*)(ws + 2546688);  // 200000*128 bf16 = 51.2 MB

    k_prep<<<50, 256, 0, stream>>>(Wq, Wk, a, Wew, Web, Wuc, wqa, wka, be, Wcomb2);
    k_scores<<<200000 / 64, 256, 0, stream>>>(mem, wqa, wka, nsq, nsk, memh);
    k_attn<<<2 * BATCH / 4, 256, 0, stream>>>(memh, nsq, nsk, src_idxs, dst_idxs,
                                              src_nb, dst_nb, agg);
    k_gemm<<<BATCH / NB, 256, 0, stream>>>(mem, edge_feat, Wuc, Wcomb2, be, agg,
                                           Wc1, Wc2,
                                           src_idxs, dst_idxs, edge_idxs, out);
}